// Round 8
// baseline (2020.197 us; speedup 1.0000x reference)
//
#include <hip/hip_runtime.h>
#include <math.h>

#define Bb 16
#define Nn 2048
#define Dd 256
#define Cc 128
#define Kk 20
#define BIG_NEG -1.0e9f

// workspace layout (float offsets)
#define WS_EMIS   0
#define WS_MSC    (WS_EMIS + Bb*Nn*Cc)          // means * inv_var, bf16  [C][D]
#define WS_XQ     (WS_MSC + Cc*Dd)              // xq, then me[b*Nn+t] after esc_kernel
#define WS_ECHAN  (WS_XQ + Bb*Nn)               // const - 0.5*mq   [C]
#define WS_T      (WS_ECHAN + Cc)               // exp(trans_lp)    [C][C]
#define WS_LEN    (WS_T + Cc*Cc)                // len_lp           [K][C]
#define WS_INIT   (WS_LEN + Kk*Cc)              // init_lp          [C]
#define WS_IVAR   (WS_INIT + Cc)                // 1/cov            [D]

typedef __attribute__((ext_vector_type(8))) short short8;
typedef __attribute__((ext_vector_type(4))) float float4v;
typedef __attribute__((ext_vector_type(2))) float float2v;
typedef __attribute__((ext_vector_type(8))) unsigned short u16x8;
typedef __attribute__((ext_vector_type(4))) unsigned short u16x4;
typedef __attribute__((ext_vector_type(2))) unsigned short u16x2;

__device__ __forceinline__ unsigned short f32_to_bf16(float x) {
  unsigned int u = __builtin_bit_cast(unsigned int, x);
  u = (u + 0x7FFFu + ((u >> 16) & 1u)) >> 16;
  return (unsigned short)u;
}

#define DPP_STEP(x, op, ctrl, rmask)                                          \
  do {                                                                        \
    int _yi = __builtin_amdgcn_update_dpp(                                    \
        __builtin_bit_cast(int, x), __builtin_bit_cast(int, x), ctrl, rmask,  \
        0xF, true);                                                           \
    x = op(x, __builtin_bit_cast(float, _yi));                                \
  } while (0)

__device__ __forceinline__ float dpp_add(float a, float b) { return a + b; }

__device__ __forceinline__ float wave_max64(float x) {
  DPP_STEP(x, fmaxf, 0xB1, 0xF);
  DPP_STEP(x, fmaxf, 0x4E, 0xF);
  DPP_STEP(x, fmaxf, 0x141, 0xF);
  DPP_STEP(x, fmaxf, 0x140, 0xF);
  DPP_STEP(x, fmaxf, 0x142, 0xA);
  DPP_STEP(x, fmaxf, 0x143, 0xC);
  return __builtin_bit_cast(float,
      __builtin_amdgcn_readlane(__builtin_bit_cast(int, x), 63));
}

__device__ __forceinline__ float wave_sum64(float x) {
  DPP_STEP(x, dpp_add, 0xB1, 0xF);
  DPP_STEP(x, dpp_add, 0x4E, 0xF);
  DPP_STEP(x, dpp_add, 0x141, 0xF);
  DPP_STEP(x, dpp_add, 0x140, 0xF);
  DPP_STEP(x, dpp_add, 0x142, 0xA);
  DPP_STEP(x, dpp_add, 0x143, 0xC);
  return __builtin_bit_cast(float,
      __builtin_amdgcn_readlane(__builtin_bit_cast(int, x), 63));
}

// max over the 128 bf16 p-values held in the 4 fragments (bf16 >= 0 -> u16 monotone)
__device__ __forceinline__ float frag_max_to_f32(short8 a, short8 b, short8 c, short8 d) {
  u16x8 ua = __builtin_bit_cast(u16x8, a), ub = __builtin_bit_cast(u16x8, b);
  u16x8 uc = __builtin_bit_cast(u16x8, c), ud = __builtin_bit_cast(u16x8, d);
  u16x8 m8 = __builtin_elementwise_max(__builtin_elementwise_max(ua, ub),
                                       __builtin_elementwise_max(uc, ud));
  u16x4 lo4 = __builtin_shufflevector(m8, m8, 0, 1, 2, 3);
  u16x4 hi4 = __builtin_shufflevector(m8, m8, 4, 5, 6, 7);
  u16x4 m4 = __builtin_elementwise_max(lo4, hi4);
  u16x2 lo2 = __builtin_shufflevector(m4, m4, 0, 1);
  u16x2 hi2 = __builtin_shufflevector(m4, m4, 2, 3);
  u16x2 m2 = __builtin_elementwise_max(lo2, hi2);
  unsigned mm = (unsigned)m2[0];
  unsigned m1 = (unsigned)m2[1];
  mm = mm > m1 ? mm : m1;
  {
    int y = __builtin_amdgcn_update_dpp((int)mm, (int)mm, 0x142, 0xA, 0xF, true);
    unsigned uy = (unsigned)y; mm = mm > uy ? mm : uy;
    y = __builtin_amdgcn_update_dpp((int)mm, (int)mm, 0x143, 0xC, 0xF, true);
    uy = (unsigned)y; mm = mm > uy ? mm : uy;
  }
  unsigned full = (unsigned)__builtin_amdgcn_readlane((int)mm, 63);
  return __builtin_bit_cast(float, full << 16);
}

// ---------------- small precompute (1 block, 256 threads) ----------------
__global__ void prep_kernel(const float* __restrict__ means,
                            const float* __restrict__ cov,
                            const float* __restrict__ tl,
                            const float* __restrict__ il,
                            const float* __restrict__ plr,
                            float* __restrict__ ws) {
  __shared__ float s_iv[Dd];
  __shared__ float s_red[4];
  __shared__ float s_tlse[Cc];
  int tid = threadIdx.x;

  float cv = cov[tid];
  float iv = 1.0f / cv;
  s_iv[tid] = iv;
  ws[WS_IVAR + tid] = iv;
  float lg = __logf(cv);
  #pragma unroll
  for (int off = 1; off < 64; off <<= 1) lg += __shfl_xor(lg, off, 64);
  if ((tid & 63) == 0) s_red[tid >> 6] = lg;
  __syncthreads();
  float logdet = s_red[0] + s_red[1] + s_red[2] + s_red[3];
  float cconst = -0.5f * ((float)Dd * 1.8378770664093453f + logdet);

  unsigned short* mscb = (unsigned short*)(ws + WS_MSC);
  for (int idx = tid; idx < Cc * Dd; idx += 256) {
    int d = idx & (Dd - 1);
    mscb[idx] = f32_to_bf16(means[idx] * s_iv[d]);
  }
  if (tid < Cc) {
    float acc = 0.0f;
    for (int d = 0; d < Dd; d++) {
      float m = means[tid * Dd + d];
      acc = fmaf(m * m, s_iv[d], acc);
    }
    ws[WS_ECHAN + tid] = cconst - 0.5f * acc;
  }
  for (int idx = tid; idx < Kk * Cc; idx += 256) {
    int L = idx / Cc + 1;
    int c = idx & (Cc - 1);
    float r = plr[c];
    ws[WS_LEN + idx] = (float)L * r - __expf(r) - lgammaf((float)(L + 1));
  }

  __syncthreads();
  float x = (tid < Cc) ? il[tid] : -INFINITY;
  float mx = x;
  #pragma unroll
  for (int off = 1; off < 64; off <<= 1) mx = fmaxf(mx, __shfl_xor(mx, off, 64));
  if ((tid & 63) == 0) s_red[tid >> 6] = mx;
  __syncthreads();
  float M = fmaxf(s_red[0], s_red[1]);
  float se = (tid < Cc) ? __expf(x - M) : 0.0f;
  #pragma unroll
  for (int off = 1; off < 64; off <<= 1) se += __shfl_xor(se, off, 64);
  __syncthreads();
  if ((tid & 63) == 0) s_red[tid >> 6] = se;
  __syncthreads();
  float lse = M + __logf(s_red[0] + s_red[1]);
  if (tid < Cc) ws[WS_INIT + tid] = x - lse;

  if (tid < Cc) {
    int j = tid;
    float m2 = -INFINITY;
    for (int i = 0; i < Cc; i++) if (i != j) m2 = fmaxf(m2, tl[i * Cc + j]);
    float s2 = 0.0f;
    for (int i = 0; i < Cc; i++) if (i != j) s2 += __expf(tl[i * Cc + j] - m2);
    s_tlse[j] = m2 + __logf(s2);
  }
  __syncthreads();
  for (int idx = tid; idx < Cc * Cc; idx += 256) {
    int i = idx / Cc;
    int j = idx & (Cc - 1);
    ws[WS_T + idx] = (i == j) ? 0.0f : __expf(tl[idx] - s_tlse[j]);
  }
}

// ---------------- xq[b,n] = sum_d f^2 * inv_var (one wave per position) ----------------
__global__ void xq_kernel(const float* __restrict__ f, float* __restrict__ ws) {
  int pos = blockIdx.x * 4 + (threadIdx.x >> 6);
  int lane = threadIdx.x & 63;
  const float4 fv = *(const float4*)&f[(size_t)pos * Dd + lane * 4];
  const float4 vv = *(const float4*)&ws[WS_IVAR + lane * 4];
  float a = fv.x * fv.x * vv.x + fv.y * fv.y * vv.y +
            fv.z * fv.z * vv.z + fv.w * fv.w * vv.w;
  #pragma unroll
  for (int off = 1; off < 64; off <<= 1) a += __shfl_xor(a, off, 64);
  if (lane == 0) ws[WS_XQ + pos] = a;
}

// ---------------- emission via MFMA: 32n x 128c per block, 4 waves ----------------
__launch_bounds__(256)
__global__ void emis_mfma_kernel(const float* __restrict__ f, float* __restrict__ ws) {
  const unsigned short* msc = (const unsigned short*)(ws + WS_MSC);
  float* emis = ws + WS_EMIS;
  int tid = threadIdx.x;
  int w = tid >> 6, lane = tid & 63, g = lane >> 4, l16 = lane & 15;
  int b = blockIdx.x >> 6;
  int n0 = (blockIdx.x & 63) << 5;
  int c0 = w << 5;

  const float* fbase = f + (size_t)(b * Nn + n0) * Dd;
  float4v acc[2][2];
  #pragma unroll
  for (int rt = 0; rt < 2; rt++)
    #pragma unroll
    for (int ct = 0; ct < 2; ct++) acc[rt][ct] = (float4v){0.f, 0.f, 0.f, 0.f};

  #pragma unroll
  for (int k0 = 0; k0 < Dd; k0 += 32) {
    int kk = k0 + g * 8;
    short8 afr[2], bfr[2];
    #pragma unroll
    for (int rt = 0; rt < 2; rt++) {
      const float* src = fbase + (size_t)(rt * 16 + l16) * Dd + kk;
      float4 v0 = *(const float4*)src;
      float4 v1 = *(const float4*)(src + 4);
      short8 fr;
      fr[0] = (short)f32_to_bf16(v0.x); fr[1] = (short)f32_to_bf16(v0.y);
      fr[2] = (short)f32_to_bf16(v0.z); fr[3] = (short)f32_to_bf16(v0.w);
      fr[4] = (short)f32_to_bf16(v1.x); fr[5] = (short)f32_to_bf16(v1.y);
      fr[6] = (short)f32_to_bf16(v1.z); fr[7] = (short)f32_to_bf16(v1.w);
      afr[rt] = fr;
    }
    #pragma unroll
    for (int ct = 0; ct < 2; ct++)
      bfr[ct] = *(const short8*)&msc[(size_t)(c0 + ct * 16 + l16) * Dd + kk];
    #pragma unroll
    for (int rt = 0; rt < 2; rt++)
      #pragma unroll
      for (int ct = 0; ct < 2; ct++)
        acc[rt][ct] = __builtin_amdgcn_mfma_f32_16x16x32_bf16(afr[rt], bfr[ct], acc[rt][ct], 0, 0, 0);
  }

  #pragma unroll
  for (int rt = 0; rt < 2; rt++) {
    #pragma unroll
    for (int ct = 0; ct < 2; ct++) {
      int cc = c0 + ct * 16 + l16;
      float ec = ws[WS_ECHAN + cc];
      #pragma unroll
      for (int r = 0; r < 4; r++) {
        int row = rt * 16 + g * 4 + r;
        int nn = n0 + row;
        emis[(size_t)(b * Nn + nn) * Cc + cc] =
            ec - 0.5f * ws[WS_XQ + b * Nn + nn] + acc[rt][ct][r];
      }
    }
  }
}

// ---------------- esc transform: per emission row, IN PLACE ----------------
// Writes packed bf16 eesc pairs in the scan's lane layout into the first 64 dwords of
// the row it just read (read-before-write ordered by the exp data dependency + wave-wide
// vmcnt), and the row max me into WS_XQ (xq is dead after emis_mfma). One wave per row.
__global__ void esc_kernel(float* __restrict__ ws) {
  int row = blockIdx.x * 4 + (threadIdx.x >> 6);
  int lane = threadIdx.x & 63;
  int c0 = ((lane >> 4) << 5) + (lane & 15);
  int c1 = c0 + 16;
  float* rp = ws + WS_EMIS + (size_t)row * Cc;
  float e0 = rp[c0];
  float e1 = rp[c1];
  float m = wave_max64(fmaxf(e0, e1));
  unsigned p0 = (unsigned)f32_to_bf16(__expf(e0 - m));
  unsigned p1 = (unsigned)f32_to_bf16(__expf(e1 - m));
  ((unsigned*)rp)[lane] = p0 | (p1 << 16);
  if (lane == 0) ws[WS_XQ + row] = m;
}

// ---------------- semi-Markov scan: ONE WAVE, no barriers, minimal step ----------------
// Verified round-3/7 algebra with r=1 inside each 8-step group (renorm at group
// boundaries; drift bound <= 128^8 = e^39, safe in f32/bf16 exponent range) and the
// accounting identity a = A + me_t + log v_t (A = sum me + sum log wv; the old cum/Kahan
// machinery computed A - cum then re-added cum -- dropped; f32 error O(1) << 1.9e4 thr).
// Per step: 1 dword esc load (prefetched) -> S = pk_fma(q, elen0, Stail) -> v = S*esc ->
// 2 ds_write_b16 -> lgkm -> 4 ds_read_b128 -> 32 independent MFMAs (T in registers) ->
// reduce/select -> q; E-shift/Stail as packed float2 ops. No expf/log/wave_max per step.
__launch_bounds__(64, 1)
__global__ void scan_kernel(const int* __restrict__ lengths,
                            const float* __restrict__ ws,
                            float* __restrict__ out) {
  __shared__ __align__(16) unsigned short p_lds[Cc];   // 256 B, same-wave use

  int lane = threadIdx.x;
  int g = lane >> 4;
  int l15 = lane & 15;
  int c0 = g * 32 + l15;
  int c1 = c0 + 16;
  int b = blockIdx.x;
  int len_b = lengths[b];
  const unsigned* escp = (const unsigned*)(ws + WS_EMIS);
  const float* mep = ws + WS_XQ + b * Nn;

  // T fragments in REGISTERS (round-3 mapping, verified): lane holds
  // T[nt*16 + l15][kc*32 + g*8 + j]
  short8 Tf[8][4];
  {
    const float* T = ws + WS_T;
    #pragma unroll
    for (int nt = 0; nt < 8; nt++)
      #pragma unroll
      for (int kc = 0; kc < 4; kc++) {
        const float* src = &T[(size_t)(nt * 16 + l15) * Cc + kc * 32 + g * 8];
        short8 fr;
        #pragma unroll
        for (int j = 0; j < 8; j++) fr[j] = (short)f32_to_bf16(src[j]);
        Tf[nt][kc] = fr;
      }
  }

  float2v elen[Kk];
  #pragma unroll
  for (int k = 0; k < Kk; k++)
    elen[k] = (float2v){__expf(ws[WS_LEN + k * Cc + c0]),
                        __expf(ws[WS_LEN + k * Cc + c1])};

  float2v E[Kk - 1];
  #pragma unroll
  for (int s = 0; s < Kk - 1; s++) E[s] = (float2v){0.0f, 0.0f};

  float2v q = (float2v){__expf(ws[WS_INIT + c0]), __expf(ws[WS_INIT + c1])};
  float2v Stail = (float2v){0.0f, 0.0f};
  float A = 0.0f;                      // running log-scale: sum me + sum log wv

  // group esc/me prefetch: step t = tg+i uses row (t-1)
  unsigned ed[8], edn[8];
  float meL, meLn;
  #pragma unroll
  for (int j = 0; j < 8; j++)
    ed[j] = escp[(size_t)(b * Nn + j) * Cc + lane];
  meL = (lane < 8) ? mep[lane] : 0.0f;

  short8 pa0, pa1, pa2, pa3;
  bool done = false;
  for (int tg = 1; tg <= Nn && !done; tg += 8) {
    #pragma unroll
    for (int i = 0; i < 8; i++) {
      int t = tg + i;
      unsigned e32 = ed[i];
      float2v escv = (float2v){
          __builtin_bit_cast(float, e32 << 16),
          __builtin_bit_cast(float, e32 & 0xFFFF0000u)};
      float mei = __builtin_bit_cast(float,
          __builtin_amdgcn_readlane(__builtin_bit_cast(int, meL), i));
      float2v S = q * elen[0] + Stail;
      float2v v = S * escv;

      if (t == len_b) {
        float ax = A + mei + __logf(fmaxf(v.x, 1e-37f));
        float ay = A + mei + __logf(fmaxf(v.y, 1e-37f));
        float Mb = wave_max64(fmaxf(ax, ay));
        float ps = wave_sum64(__expf(ax - Mb) + __expf(ay - Mb));
        if (lane == 0) out[b] = Mb + __logf(ps);
        done = true;
        break;
      }

      // p exchange through 256 B of LDS (unnormalized bf16 trunc; scale-free)
      p_lds[c0] = (unsigned short)(__builtin_bit_cast(unsigned, v.x) >> 16);
      p_lds[c1] = (unsigned short)(__builtin_bit_cast(unsigned, v.y) >> 16);
      asm volatile("s_waitcnt lgkmcnt(0)" ::: "memory");
      pa0 = *(const short8*)&p_lds[g * 8];
      pa1 = *(const short8*)&p_lds[32 + g * 8];
      pa2 = *(const short8*)&p_lds[64 + g * 8];
      pa3 = *(const short8*)&p_lds[96 + g * 8];

      if (i == 0) {   // prefetch next group's rows tg+7 .. tg+14
        #pragma unroll
        for (int j = 0; j < 8; j++) {
          int rr = tg + 7 + j; if (rr > Nn - 1) rr = Nn - 1;
          edn[j] = escp[(size_t)(b * Nn + rr) * Cc + lane];
        }
        int rm = tg + 7 + lane; if (rm > Nn - 1) rm = Nn - 1;
        meLn = (lane < 8) ? mep[rm] : 0.0f;
      }

      // matvec: 8 tiles x 4 independent MFMAs (acc = 0), tree-reduced
      float4v z = {0.0f, 0.0f, 0.0f, 0.0f};
      float qv[8];
      #pragma unroll
      for (int nt = 0; nt < 8; nt++) {
        float4v m0 = __builtin_amdgcn_mfma_f32_16x16x32_bf16(pa0, Tf[nt][0], z, 0, 0, 0);
        float4v m1 = __builtin_amdgcn_mfma_f32_16x16x32_bf16(pa1, Tf[nt][1], z, 0, 0, 0);
        float4v m2 = __builtin_amdgcn_mfma_f32_16x16x32_bf16(pa2, Tf[nt][2], z, 0, 0, 0);
        float4v m3 = __builtin_amdgcn_mfma_f32_16x16x32_bf16(pa3, Tf[nt][3], z, 0, 0, 0);
        qv[nt] = (m0[0] + m1[0]) + (m2[0] + m3[0]);
      }

      // E-window shift + Stail (uses OLD q; multiplier = esc of this step since r=1)
      #pragma unroll
      for (int s = Kk - 2; s >= 1; s--) E[s] = E[s - 1] * escv;
      E[0] = q * escv;

      float2v s0 = E[0] * elen[1];
      float2v s1 = E[1] * elen[2];
      float2v s2 = E[2] * elen[3];
      float2v s3 = E[3] * elen[4];
      s0 = E[4] * elen[5] + s0;   s1 = E[5] * elen[6] + s1;
      s2 = E[6] * elen[7] + s2;   s3 = E[7] * elen[8] + s3;
      s0 = E[8] * elen[9] + s0;   s1 = E[9] * elen[10] + s1;
      s2 = E[10] * elen[11] + s2; s3 = E[11] * elen[12] + s3;
      s0 = E[12] * elen[13] + s0; s1 = E[13] * elen[14] + s1;
      s2 = E[14] * elen[15] + s2; s3 = E[15] * elen[16] + s3;
      s0 = E[16] * elen[17] + s0; s1 = E[17] * elen[18] + s1;
      s2 = E[18] * elen[19] + s2;
      Stail = (s0 + s1) + (s2 + s3);

      A += mei;   // accounting: scale grew by me_t this step (wv folded at boundary)

      // in-lane select: q[c0] = tile 2g, q[c1] = tile 2g+1 (col l15; rows replicated)
      float q0 = (g & 2) ? ((g & 1) ? qv[6] : qv[4]) : ((g & 1) ? qv[2] : qv[0]);
      float q1 = (g & 2) ? ((g & 1) ? qv[7] : qv[5]) : ((g & 1) ? qv[3] : qv[1]);
      q = (float2v){q0, q1};
    }
    if (!done) {
      // group-boundary renorm from the last step's p fragments
      float wv = fmaxf(frag_max_to_f32(pa0, pa1, pa2, pa3), 1.0e-30f);
      float r = __builtin_amdgcn_rcpf(wv);
      q = q * r;
      Stail = Stail * r;
      #pragma unroll
      for (int s = 0; s < Kk - 1; s++) E[s] = E[s] * r;
      A += __logf(wv);
      #pragma unroll
      for (int j = 0; j < 8; j++) ed[j] = edn[j];
      meL = meLn;
    }
  }
}

extern "C" void kernel_launch(void* const* d_in, const int* in_sizes, int n_in,
                              void* d_out, int out_size, void* d_ws, size_t ws_size,
                              hipStream_t stream) {
  const float* features = (const float*)d_in[0];
  const int* lengths = (const int*)d_in[1];
  const float* means = (const float*)d_in[2];
  const float* cov = (const float*)d_in[3];
  const float* tl = (const float*)d_in[4];
  const float* il = (const float*)d_in[5];
  const float* plr = (const float*)d_in[6];
  float* out = (float*)d_out;
  float* ws = (float*)d_ws;

  prep_kernel<<<1, 256, 0, stream>>>(means, cov, tl, il, plr, ws);
  xq_kernel<<<(Bb * Nn) / 4, 256, 0, stream>>>(features, ws);
  emis_mfma_kernel<<<Bb * (Nn / 32), 256, 0, stream>>>(features, ws);
  esc_kernel<<<(Bb * Nn) / 4, 256, 0, stream>>>(ws);
  scan_kernel<<<Bb, 64, 0, stream>>>(lengths, ws, out);
}